// Round 1
// baseline (18920.508 us; speedup 1.0000x reference)
//
#include <hip/hip_runtime.h>

// Problem constants
namespace {
constexpr int Bc = 4, Tc = 1024, Hc = 4, Dc = 256, DHc = 1024, Lc = 6, Vc = 256;
constexpr int HALFc = 512;  // Dh/2 for RoPE
constexpr float EPS = 1e-5f;

// GEMM tile config
constexpr int BMt = 128, BNt = 128, BKt = 16, PADt = 4;

// ---------------------------------------------------------------------------
// Generic fp32 tiled GEMM. C[m,n] = sum_k A[m,k] * B[k,n]  (or B[n,k] if TRANSB)
// EPI: 0 = none, 1 = relu, 2 = relu * aux (aux has C's layout), 3 = C += acc
// Batched over blockIdx.z with per-operand strides.
// All of M, N assumed multiples of 128; K multiple of 16 (true for all calls).
// ---------------------------------------------------------------------------
template<bool TRANSB, int EPI>
__global__ __launch_bounds__(256)
void gemm_f32(const float* __restrict__ A, long long sA,
              const float* __restrict__ Bp, long long sB,
              float* __restrict__ C, long long sC,
              const float* __restrict__ aux,
              int K, int lda, int ldb, int ldc)
{
  A  += (long long)blockIdx.z * sA;
  Bp += (long long)blockIdx.z * sB;
  C  += (long long)blockIdx.z * sC;
  if (EPI == 2) aux += (long long)blockIdx.z * sC;  // aux shares C layout

  // Transposed-in-LDS tiles: As[k][m], Bs[k][n]; row stride 132 floats
  // (528B, 16B-aligned so inner reads fuse to ds_read_b128; 132%32=4 keeps
  // transposed stores at <=2-way bank aliasing which is free on CDNA4).
  __shared__ __align__(16) float As[BKt][BMt + PADt];
  __shared__ __align__(16) float Bs[BKt][BNt + PADt];

  const int m0 = blockIdx.y * BMt;
  const int n0 = blockIdx.x * BNt;
  const int tid = threadIdx.x;
  const int tx = tid & 15;
  const int ty = tid >> 4;

  float acc[8][8] = {};

  for (int k0 = 0; k0 < K; k0 += BKt) {
    // A tile: 128 rows x 16 k, stored transposed As[k][m]
    #pragma unroll
    for (int i = tid; i < BMt * BKt; i += 256) {
      const int m = i >> 4, k = i & 15;
      As[k][m] = A[(long long)(m0 + m) * lda + (k0 + k)];
    }
    if (!TRANSB) {
      // B tile: 16 k-rows x 128 n (contiguous in n -> coalesced)
      #pragma unroll
      for (int i = tid; i < BKt * BNt; i += 256) {
        const int k = i >> 7, n = i & 127;
        Bs[k][n] = Bp[(long long)(k0 + k) * ldb + (n0 + n)];
      }
    } else {
      // B tile from row-major B[n,k]: read 16-contig k per n, store transposed
      #pragma unroll
      for (int i = tid; i < BNt * BKt; i += 256) {
        const int n = i >> 4, k = i & 15;
        Bs[k][n] = Bp[(long long)(n0 + n) * ldb + (k0 + k)];
      }
    }
    __syncthreads();

    #pragma unroll
    for (int kk = 0; kk < BKt; ++kk) {
      float av[8], bv[8];
      #pragma unroll
      for (int i = 0; i < 8; ++i) av[i] = As[kk][ty * 8 + i];
      #pragma unroll
      for (int j = 0; j < 8; ++j) bv[j] = Bs[kk][tx * 8 + j];
      #pragma unroll
      for (int i = 0; i < 8; ++i)
        #pragma unroll
        for (int j = 0; j < 8; ++j)
          acc[i][j] = fmaf(av[i], bv[j], acc[i][j]);
    }
    __syncthreads();
  }

  #pragma unroll
  for (int i = 0; i < 8; ++i) {
    const long long m = m0 + ty * 8 + i;
    #pragma unroll
    for (int j = 0; j < 8; ++j) {
      const int n = n0 + tx * 8 + j;
      float val = acc[i][j];
      if (EPI == 1) val = fmaxf(val, 0.0f);
      if (EPI == 2) val = fmaxf(val, 0.0f) * aux[m * ldc + n];
      if (EPI == 3) val += C[m * ldc + n];
      C[m * ldc + n] = val;
    }
  }
}

// ---------------------------------------------------------------------------
// RoPE tables: cos/sin[t, j] = cos/sin(t * 10000^(-j/512)), j in [0,512)
// ---------------------------------------------------------------------------
__global__ __launch_bounds__(256)
void init_tables(float* __restrict__ cosT, float* __restrict__ sinT)
{
  const int i = blockIdx.x * 256 + threadIdx.x;  // < T*512
  const int j = i & (HALFc - 1);
  const int t = i >> 9;
  const float inv = __expf(-(float)j * (9.210340371976184f / 512.0f)) * 0.0f +
                    expf(-(float)j * (9.210340371976184f / 512.0f));  // ln(10000)/512
  const float ang = (float)t * inv;
  cosT[i] = cosf(ang);
  sinT[i] = sinf(ang);
}

// ---------------------------------------------------------------------------
// RoPE apply: xr[...,e] = x[e]*c - x[e+512]*s ; xr[...,e+512] = x[e+512]*c + x[e]*s
// (cos table's two halves are identical, so one table lookup serves the pair)
// ---------------------------------------------------------------------------
__global__ __launch_bounds__(256)
void rope_kernel(const float* __restrict__ x, float* __restrict__ xr,
                 const float* __restrict__ cosT, const float* __restrict__ sinT)
{
  const int i = blockIdx.x * 256 + threadIdx.x;  // < B*T*512
  const int e = i & (HALFc - 1);
  const int bt = i >> 9;
  const int t = bt & (Tc - 1);
  const float c = cosT[t * HALFc + e];
  const float sv = sinT[t * HALFc + e];
  const long long base = (long long)bt * DHc;
  const float x0 = x[base + e];
  const float x1 = x[base + e + HALFc];
  xr[base + e] = x0 * c - x1 * sv;
  xr[base + e + HALFc] = x1 * c + x0 * sv;
}

// ---------------------------------------------------------------------------
// Block-wide (256 threads = 4 waves) mean / inv-std over D=256 elements
// ---------------------------------------------------------------------------
__device__ inline void block_stats(float val, float* red, float& mean, float& inv_std)
{
  float s1 = val, s2 = val * val;
  #pragma unroll
  for (int o = 1; o < 64; o <<= 1) {
    s1 += __shfl_xor(s1, o);
    s2 += __shfl_xor(s2, o);
  }
  const int lane = threadIdx.x & 63;
  const int w = threadIdx.x >> 6;
  if (lane == 0) { red[w * 2] = s1; red[w * 2 + 1] = s2; }
  __syncthreads();
  s1 = red[0] + red[2] + red[4] + red[6];
  s2 = red[1] + red[3] + red[5] + red[7];
  mean = s1 * (1.0f / Dc);
  const float var = s2 * (1.0f / Dc) - mean * mean;
  inv_std = 1.0f / sqrtf(var + EPS);
  __syncthreads();  // allow red reuse
}

// v[row,:] = LN(emb_w[tokens[row],:])
__global__ __launch_bounds__(256)
void embed_ln(const int* __restrict__ tokens, const float* __restrict__ emb,
              float* __restrict__ v)
{
  __shared__ float red[8];
  const int row = blockIdx.x;       // B*T rows
  const int d = threadIdx.x;        // D = 256
  const int tok = tokens[row];
  const float val = emb[tok * Dc + d];
  float m, is;
  block_stats(val, red, m, is);
  v[(long long)row * Dc + d] = (val - m) * is;
}

// v[row,:] = LN(v[row,:] + LN(t[row,:]))
__global__ __launch_bounds__(256)
void fuse_ln(float* __restrict__ v, const float* __restrict__ t)
{
  __shared__ float red[8];
  const long long row = blockIdx.x;
  const int d = threadIdx.x;
  const float tv = t[row * Dc + d];
  float m1, is1;
  block_stats(tv, red, m1, is1);
  const float u = (tv - m1) * is1;
  const float w = v[row * Dc + d] + u;
  float m2, is2;
  block_stats(w, red, m2, is2);
  v[row * Dc + d] = (w - m2) * is2;
}

}  // anonymous namespace

extern "C" void kernel_launch(void* const* d_in, const int* in_sizes, int n_in,
                              void* d_out, int out_size, void* d_ws, size_t ws_size,
                              hipStream_t stream)
{
  (void)in_sizes; (void)n_in; (void)out_size; (void)ws_size;
  const int*   tokens  = (const int*)d_in[0];
  const float* emb_w   = (const float*)d_in[1];
  const float* E       = (const float*)d_in[2];
  const float* Dx      = (const float*)d_in[3];
  const float* Dy      = (const float*)d_in[4];
  const float* readout = (const float*)d_in[5];
  float* out = (float*)d_out;

  // Workspace carve-up: 16,777,216 floats = 64 MB total
  float* ws   = (float*)d_ws;
  float* cosT = ws;  ws += (long long)Tc * HALFc;   // 0.5M
  float* sinT = ws;  ws += (long long)Tc * HALFc;   // 0.5M
  float* v    = ws;  ws += (long long)Bc * Tc * Dc;  // 1M
  float* x    = ws;  ws += (long long)Bc * Tc * DHc; // 4M
  float* xr   = ws;  ws += (long long)Bc * Tc * DHc; // 4M (reused as y)
  float* s    = ws;  ws += (long long)Bc * Tc * Tc;  // 4M
  float* a    = ws;  ws += (long long)Bc * Tc * Dc;  // 1M
  float* t    = ws;  ws += (long long)Bc * Tc * Dc;  // 1M

  init_tables<<<(Tc * HALFc) / 256, 256, 0, stream>>>(cosT, sinT);
  embed_ln<<<Bc * Tc, 256, 0, stream>>>(tokens, emb_w, v);

  for (int l = 0; l < Lc; ++l) {
    hipMemsetAsync(t, 0, (size_t)Bc * Tc * Dc * sizeof(float), stream);
    for (int h = 0; h < Hc; ++h) {
      const float* Dxh = Dx + (long long)h * Dc * DHc;  // [D, Dh]
      const float* Dyh = Dy + (long long)h * Dc * DHc;  // [D, Dh]
      const float* Eh  = E  + (long long)h * DHc * Dc;  // [Dh, D]

      // 1) x = relu(v · Dxh)   [T x Dh], K = D, batched over b
      gemm_f32<false, 1><<<dim3(DHc / BNt, Tc / BMt, Bc), 256, 0, stream>>>(
          v, (long long)Tc * Dc, Dxh, 0, x, (long long)Tc * DHc, nullptr,
          Dc, Dc, DHc, DHc);

      // 2) xr = RoPE(x)
      rope_kernel<<<(Bc * Tc * HALFc) / 256, 256, 0, stream>>>(x, xr, cosT, sinT);

      // 3) s = xr · xr^T   [T x T], K = Dh
      gemm_f32<true, 0><<<dim3(Tc / BNt, Tc / BMt, Bc), 256, 0, stream>>>(
          xr, (long long)Tc * DHc, xr, (long long)Tc * DHc, s, (long long)Tc * Tc,
          nullptr, DHc, DHc, DHc, Tc);

      // 4) a = s · v   [T x D], K = T
      gemm_f32<false, 0><<<dim3(Dc / BNt, Tc / BMt, Bc), 256, 0, stream>>>(
          s, (long long)Tc * Tc, v, (long long)Tc * Dc, a, (long long)Tc * Dc,
          nullptr, Tc, Tc, Dc, Dc);

      // 5) y = relu(a · Dyh) * x   [T x Dh], K = D  (y overwrites xr buffer)
      gemm_f32<false, 2><<<dim3(DHc / BNt, Tc / BMt, Bc), 256, 0, stream>>>(
          a, (long long)Tc * Dc, Dyh, 0, xr, (long long)Tc * DHc, x,
          Dc, Dc, DHc, DHc);

      // 6) t += y · Eh   [T x D], K = Dh
      gemm_f32<false, 3><<<dim3(Dc / BNt, Tc / BMt, Bc), 256, 0, stream>>>(
          xr, (long long)Tc * DHc, Eh, 0, t, (long long)Tc * Dc, nullptr,
          DHc, DHc, Dc, Dc);
    }
    // v = LN(v + LN(t))
    fuse_ln<<<Bc * Tc, 256, 0, stream>>>(v, t);
  }

  // out = v · readout   [B*T x V], K = D
  gemm_f32<false, 0><<<dim3(Vc / BNt, (Bc * Tc) / BMt, 1), 256, 0, stream>>>(
      v, 0, readout, 0, out, 0, nullptr,
      Dc, Dc, Vc, Vc);
}

// Round 2
// 2447.256 us; speedup vs baseline: 7.7313x; 7.7313x over previous
//
#include <hip/hip_runtime.h>
#include <cstdint>

namespace {

typedef _Float16 f16_t;
typedef _Float16 f16x8 __attribute__((ext_vector_type(8)));
typedef _Float16 f16x4 __attribute__((ext_vector_type(4)));
typedef float    f32x4 __attribute__((ext_vector_type(4)));

constexpr int Bc = 4, Tc = 1024, Hc = 4, Dc = 256, DHc = 1024, Lc = 6, Vc = 256;
constexpr int HALFc = 512;
constexpr float EPS = 1e-5f;

// Async global->LDS, 16B per lane. LDS dest must be linear in lane order
// (wave-uniform base + lane*16); swizzling is done on the GLOBAL source
// address + the ds_read side (both-sides-or-neither, same involution).
__device__ __forceinline__ void gload16(const void* g, void* l) {
  __builtin_amdgcn_global_load_lds((const __attribute__((address_space(1))) void*)g,
                                   (__attribute__((address_space(3))) void*)l, 16, 0, 0);
}

// ---------------------------------------------------------------------------
// MFMA f16 GEMM: C = A(MxK) * B^T, B stored [N][K]; A,B f16 k-contiguous.
// 128x128 tile, BK=64, 4 waves (2x2 of 64x64), v_mfma_f32_16x16x32_f16.
// LDS tiles [128 rows][64 k] f16 (128B rows), XOR-swizzled: 16B-slot index
// s is stored at s ^ (row&7)  -> ds_read_b128 lands 2-way on banks (free).
// EPI: 0 = f16, 1 = relu->f16, 2 = relu*aux->f16, 3 = +=fp32, 4 = fp32
// Batched over blockIdx.z via element strides sA/sB/sC (aux shares sC).
// M,N multiples of 128; K multiple of 64.
// ---------------------------------------------------------------------------
template<int EPI>
__global__ __launch_bounds__(256)
void gemm_f16(const f16_t* __restrict__ A, long long sA,
              const f16_t* __restrict__ B, long long sB,
              void* __restrict__ Cv, long long sC,
              const f16_t* __restrict__ aux,
              int K, int lda, int ldb, int ldc)
{
  __shared__ __align__(16) f16_t As[128 * 64];
  __shared__ __align__(16) f16_t Bs[128 * 64];

  A += (long long)blockIdx.z * sA;
  B += (long long)blockIdx.z * sB;

  const int tid  = threadIdx.x;
  const int lane = tid & 63;
  const int wave = tid >> 6;
  const int wr = wave >> 1, wc = wave & 1;   // wave -> 64x64 quadrant
  const int m0 = blockIdx.y * 128, n0 = blockIdx.x * 128;

  const int lrow  = tid >> 3;   // 0..31 (row within a 32-row staging pass)
  const int lslot = tid & 7;    // 16B slot within 128B row

  f32x4 acc[4][4] = {};

  for (int k0 = 0; k0 < K; k0 += 64) {
    // Stage A tile: 4 passes x 256 lanes x 16B = 128 rows x 128B.
    // LDS position (row, slot) receives global column (slot ^ (row&7))*8.
    #pragma unroll
    for (int c = 0; c < 4; ++c) {
      const int row  = c * 32 + lrow;
      const int scol = (lslot ^ (row & 7)) << 3;
      gload16(A + (size_t)(m0 + row) * lda + k0 + scol, As + (c * 256 + tid) * 8);
    }
    #pragma unroll
    for (int c = 0; c < 4; ++c) {
      const int row  = c * 32 + lrow;
      const int scol = (lslot ^ (row & 7)) << 3;
      gload16(B + (size_t)(n0 + row) * ldb + k0 + scol, Bs + (c * 256 + tid) * 8);
    }
    __syncthreads();

    #pragma unroll
    for (int ks = 0; ks < 2; ++ks) {
      f16x8 af[4], bf[4];
      #pragma unroll
      for (int m = 0; m < 4; ++m) {
        const int r  = wr * 64 + m * 16 + (lane & 15);
        const int sl = (ks * 4 + (lane >> 4)) ^ (r & 7);
        af[m] = *(const f16x8*)(As + r * 64 + sl * 8);
      }
      #pragma unroll
      for (int n = 0; n < 4; ++n) {
        const int r  = wc * 64 + n * 16 + (lane & 15);
        const int sl = (ks * 4 + (lane >> 4)) ^ (r & 7);
        bf[n] = *(const f16x8*)(Bs + r * 64 + sl * 8);
      }
      #pragma unroll
      for (int m = 0; m < 4; ++m)
        #pragma unroll
        for (int n = 0; n < 4; ++n)
          acc[m][n] = __builtin_amdgcn_mfma_f32_16x16x32_f16(af[m], bf[n], acc[m][n], 0, 0, 0);
    }
    __syncthreads();
  }

  // Epilogue. C/D frag: col = lane&15, row = (lane>>4)*4 + reg (m89-verified).
  const int cr   = (lane >> 4) * 4;
  const int ccol = lane & 15;
  if (EPI == 3 || EPI == 4) {
    float* C = (float*)Cv + (long long)blockIdx.z * sC;
    #pragma unroll
    for (int m = 0; m < 4; ++m)
      #pragma unroll
      for (int n = 0; n < 4; ++n)
        #pragma unroll
        for (int r = 0; r < 4; ++r) {
          const long long off = (long long)(m0 + wr * 64 + m * 16 + cr + r) * ldc
                                + (n0 + wc * 64 + n * 16 + ccol);
          if (EPI == 3) C[off] += acc[m][n][r];
          else          C[off]  = acc[m][n][r];
        }
  } else {
    f16_t* C = (f16_t*)Cv + (long long)blockIdx.z * sC;
    const f16_t* X = (EPI == 2) ? aux + (long long)blockIdx.z * sC : nullptr;
    #pragma unroll
    for (int m = 0; m < 4; ++m)
      #pragma unroll
      for (int n = 0; n < 4; ++n)
        #pragma unroll
        for (int r = 0; r < 4; ++r) {
          const long long off = (long long)(m0 + wr * 64 + m * 16 + cr + r) * ldc
                                + (n0 + wc * 64 + n * 16 + ccol);
          float val = acc[m][n][r];
          if (EPI >= 1) val = fmaxf(val, 0.0f);
          if (EPI == 2) val *= (float)X[off];
          C[off] = (f16_t)val;
        }
  }
}

// ---------------------------------------------------------------------------
// Tiled transpose: in fp32 [R][C] -> out f16 [C][R], batched over z.
// ---------------------------------------------------------------------------
__global__ __launch_bounds__(256)
void transpose_f32_f16(const float* __restrict__ in, f16_t* __restrict__ out,
                       int R, int C, long long sIn, long long sOut)
{
  __shared__ float tile[32][33];
  in  += (long long)blockIdx.z * sIn;
  out += (long long)blockIdx.z * sOut;
  const int c0 = blockIdx.x * 32, r0 = blockIdx.y * 32;
  const int tx = threadIdx.x & 31, ty = threadIdx.x >> 5;  // 32x8
  #pragma unroll
  for (int i = 0; i < 32; i += 8)
    tile[ty + i][tx] = in[(long long)(r0 + ty + i) * C + (c0 + tx)];
  __syncthreads();
  #pragma unroll
  for (int i = 0; i < 32; i += 8)
    out[(long long)(c0 + ty + i) * R + (r0 + tx)] = (f16_t)tile[tx][ty + i];
}

// f16 [R][C] -> f16 [C][R], batched (for vT)
__global__ __launch_bounds__(256)
void transpose_f16(const f16_t* __restrict__ in, f16_t* __restrict__ out,
                   int R, int C, long long sIn, long long sOut)
{
  __shared__ f16_t tile[32][34];
  in  += (long long)blockIdx.z * sIn;
  out += (long long)blockIdx.z * sOut;
  const int c0 = blockIdx.x * 32, r0 = blockIdx.y * 32;
  const int tx = threadIdx.x & 31, ty = threadIdx.x >> 5;
  #pragma unroll
  for (int i = 0; i < 32; i += 8)
    tile[ty + i][tx] = in[(long long)(r0 + ty + i) * C + (c0 + tx)];
  __syncthreads();
  #pragma unroll
  for (int i = 0; i < 32; i += 8)
    out[(long long)(c0 + ty + i) * R + (r0 + tx)] = tile[tx][ty + i];
}

// ---------------------------------------------------------------------------
// RoPE tables: cos/sin[t, j] = cos/sin(t * 10000^(-j/512)), fp32
// ---------------------------------------------------------------------------
__global__ __launch_bounds__(256)
void init_tables(float* __restrict__ cosT, float* __restrict__ sinT)
{
  const int i = blockIdx.x * 256 + threadIdx.x;  // < T*512
  const int j = i & (HALFc - 1);
  const int t = i >> 9;
  const float inv = expf(-(float)j * (9.210340371976184f / 512.0f));  // ln(1e4)/512
  const float ang = (float)t * inv;
  cosT[i] = cosf(ang);
  sinT[i] = sinf(ang);
}

// RoPE: xr[e] = x[e]c - x[e+512]s ; xr[e+512] = x[e+512]c + x[e]s (f16, 4/thread)
__global__ __launch_bounds__(256)
void rope_f16(const f16_t* __restrict__ x, f16_t* __restrict__ xr,
              const float* __restrict__ cosT, const float* __restrict__ sinT)
{
  const int i  = blockIdx.x * 256 + threadIdx.x;   // < B*T*128
  const int e4 = i & 127;
  const int bt = i >> 7;
  const int t  = bt & (Tc - 1);
  const f32x4 c = ((const f32x4*)cosT)[t * 128 + e4];
  const f32x4 s = ((const f32x4*)sinT)[t * 128 + e4];
  const long long base = (long long)bt * DHc + e4 * 4;
  const f16x4 x0 = *(const f16x4*)(x + base);
  const f16x4 x1 = *(const f16x4*)(x + base + HALFc);
  f16x4 r0, r1;
  #pragma unroll
  for (int j = 0; j < 4; ++j) {
    const float a = (float)x0[j], b = (float)x1[j];
    r0[j] = (f16_t)(a * c[j] - b * s[j]);
    r1[j] = (f16_t)(b * c[j] + a * s[j]);
  }
  *(f16x4*)(xr + base) = r0;
  *(f16x4*)(xr + base + HALFc) = r1;
}

// ---------------------------------------------------------------------------
// Block-wide (256 threads) mean / inv-std over D=256
// ---------------------------------------------------------------------------
__device__ __forceinline__ void block_stats(float val, float* red, float& mean, float& inv_std)
{
  float s1 = val, s2 = val * val;
  #pragma unroll
  for (int o = 1; o < 64; o <<= 1) {
    s1 += __shfl_xor(s1, o);
    s2 += __shfl_xor(s2, o);
  }
  const int lane = threadIdx.x & 63;
  const int w = threadIdx.x >> 6;
  if (lane == 0) { red[w * 2] = s1; red[w * 2 + 1] = s2; }
  __syncthreads();
  s1 = red[0] + red[2] + red[4] + red[6];
  s2 = red[1] + red[3] + red[5] + red[7];
  mean = s1 * (1.0f / Dc);
  const float var = s2 * (1.0f / Dc) - mean * mean;
  inv_std = 1.0f / sqrtf(var + EPS);
  __syncthreads();
}

// v[row,:] = LN(emb_w[tokens[row],:])  (f16 out)
__global__ __launch_bounds__(256)
void embed_ln(const int* __restrict__ tokens, const float* __restrict__ emb,
              f16_t* __restrict__ v)
{
  __shared__ float red[8];
  const int row = blockIdx.x;
  const int d = threadIdx.x;
  const float val = emb[(long long)tokens[row] * Dc + d];
  float m, is;
  block_stats(val, red, m, is);
  v[(long long)row * Dc + d] = (f16_t)((val - m) * is);
}

// v = LN(v + LN(t)); t fp32, v f16
__global__ __launch_bounds__(256)
void fuse_ln(f16_t* __restrict__ v, const float* __restrict__ t)
{
  __shared__ float red[8];
  const long long row = blockIdx.x;
  const int d = threadIdx.x;
  const float tv = t[row * Dc + d];
  float m1, is1;
  block_stats(tv, red, m1, is1);
  const float u = (tv - m1) * is1;
  const float wv = (float)v[row * Dc + d] + u;
  float m2, is2;
  block_stats(wv, red, m2, is2);
  v[row * Dc + d] = (f16_t)((wv - m2) * is2);
}

}  // anonymous namespace

extern "C" void kernel_launch(void* const* d_in, const int* in_sizes, int n_in,
                              void* d_out, int out_size, void* d_ws, size_t ws_size,
                              hipStream_t stream)
{
  (void)in_sizes; (void)n_in; (void)out_size; (void)ws_size;
  const int*   tokens  = (const int*)d_in[0];
  const float* emb_w   = (const float*)d_in[1];
  const float* E       = (const float*)d_in[2];
  const float* Dx      = (const float*)d_in[3];
  const float* Dy      = (const float*)d_in[4];
  const float* readout = (const float*)d_in[5];
  float* out = (float*)d_out;

  // Workspace carve-up (~44 MB; ws proven >= 64 MiB in round 1)
  char* w = (char*)d_ws;
  auto carve = [&](size_t bytes) { char* p = w; w += (bytes + 255) & ~(size_t)255; return p; };
  float* cosT = (float*)carve((size_t)Tc * HALFc * 4);            // 2 MB
  float* sinT = (float*)carve((size_t)Tc * HALFc * 4);            // 2 MB
  f16_t* v    = (f16_t*)carve((size_t)Bc * Tc * Dc * 2);          // 2 MB
  f16_t* vT   = (f16_t*)carve((size_t)Bc * Dc * Tc * 2);          // 2 MB
  f16_t* x    = (f16_t*)carve((size_t)Bc * Tc * DHc * 2);         // 8 MB
  f16_t* xr   = (f16_t*)carve((size_t)Bc * Tc * DHc * 2);         // 8 MB (also y)
  f16_t* s    = (f16_t*)carve((size_t)Bc * Tc * Tc * 2);          // 8 MB
  f16_t* a    = (f16_t*)carve((size_t)Bc * Tc * Dc * 2);          // 2 MB
  float* t    = (float*)carve((size_t)Bc * Tc * Dc * 4);          // 4 MB
  f16_t* DxT  = (f16_t*)carve((size_t)Hc * DHc * Dc * 2);         // 2 MB [H][Dh][D]
  f16_t* DyT  = (f16_t*)carve((size_t)Hc * DHc * Dc * 2);         // 2 MB [H][Dh][D]
  f16_t* ET   = (f16_t*)carve((size_t)Hc * Dc * DHc * 2);         // 2 MB [H][D][Dh]
  f16_t* RT   = (f16_t*)carve((size_t)Vc * Dc * 2);               // 128 KB [V][D]

  const long long TDH = (long long)Tc * DHc;  // 1M
  const long long TT  = (long long)Tc * Tc;   // 1M
  const long long TD  = (long long)Tc * Dc;   // 256K
  const long long DT  = (long long)Dc * Tc;   // 256K
  const long long HDD = (long long)DHc * Dc;  // 256K (head stride for DxT/DyT/ET)

  // Weight transposes -> f16 [N][K] layouts
  transpose_f32_f16<<<dim3(32, 8, Hc), 256, 0, stream>>>(Dx, DxT, Dc, DHc, HDD, HDD);
  transpose_f32_f16<<<dim3(32, 8, Hc), 256, 0, stream>>>(Dy, DyT, Dc, DHc, HDD, HDD);
  transpose_f32_f16<<<dim3(8, 32, Hc), 256, 0, stream>>>(E, ET, DHc, Dc, HDD, HDD);
  transpose_f32_f16<<<dim3(8, 8, 1), 256, 0, stream>>>(readout, RT, Dc, Vc, 0, 0);
  init_tables<<<(Tc * HALFc) / 256, 256, 0, stream>>>(cosT, sinT);
  embed_ln<<<Bc * Tc, 256, 0, stream>>>(tokens, emb_w, v);
  transpose_f16<<<dim3(8, 32, Bc), 256, 0, stream>>>(v, vT, Tc, Dc, TD, DT);

  for (int l = 0; l < Lc; ++l) {
    hipMemsetAsync(t, 0, (size_t)Bc * Tc * Dc * 4, stream);
    for (int h = 0; h < Hc; ++h) {
      // 1) x = relu(v . DxT[h]^T)   [4096 x 1024], K=256
      gemm_f16<1><<<dim3(8, 32, 1), 256, 0, stream>>>(
          v, 0, DxT + h * HDD, 0, x, 0, nullptr, Dc, Dc, Dc, DHc);
      // 2) xr = RoPE(x)
      rope_f16<<<(Bc * Tc * 128) / 256, 256, 0, stream>>>(x, xr, cosT, sinT);
      // 3) s = xr . xr^T per batch   [1024 x 1024], K=1024, z=B
      gemm_f16<0><<<dim3(8, 8, Bc), 256, 0, stream>>>(
          xr, TDH, xr, TDH, s, TT, nullptr, DHc, DHc, DHc, Tc);
      // 4) a = s . v per batch   [1024 x 256], K=1024 (B-operand = vT)
      gemm_f16<0><<<dim3(2, 8, Bc), 256, 0, stream>>>(
          s, TT, vT, DT, a, TD, nullptr, Tc, Tc, Tc, Dc);
      // 5) y = relu(a . DyT[h]^T) * x   [4096 x 1024], K=256 (y -> xr buffer)
      gemm_f16<2><<<dim3(8, 32, 1), 256, 0, stream>>>(
          a, 0, DyT + h * HDD, 0, xr, 0, x, Dc, Dc, Dc, DHc);
      // 6) t += y . ET[h]^T   [4096 x 256] fp32, K=1024
      gemm_f16<3><<<dim3(2, 32, 1), 256, 0, stream>>>(
          xr, 0, ET + h * HDD, 0, t, 0, nullptr, DHc, DHc, DHc, Dc);
    }
    // v = LN(v + LN(t)), then refresh vT
    fuse_ln<<<Bc * Tc, 256, 0, stream>>>(v, t);
    transpose_f16<<<dim3(8, 32, Bc), 256, 0, stream>>>(v, vT, Tc, Dc, TD, DT);
  }

  // out = v . RT^T   [4096 x 256] fp32, K=256
  gemm_f16<4><<<dim3(2, 32, 1), 256, 0, stream>>>(
      v, 0, RT, 0, out, 0, nullptr, Dc, Dc, Dc, Vc);
}

// Round 3
// 1045.247 us; speedup vs baseline: 18.1015x; 2.3413x over previous
//
#include <hip/hip_runtime.h>
#include <cstdint>

namespace {

typedef _Float16 f16_t;
typedef _Float16 f16x8 __attribute__((ext_vector_type(8)));
typedef _Float16 f16x4 __attribute__((ext_vector_type(4)));
typedef float    f32x4 __attribute__((ext_vector_type(4)));

constexpr int Bc = 4, Tc = 1024, Hc = 4, Dc = 256, DHc = 1024, Lc = 6, Vc = 256;
constexpr int HALFc = 512;
constexpr float EPS = 1e-5f;
constexpr long long TTq  = (long long)Tc * Tc;        // 1M
constexpr long long T4q  = (long long)Tc * 4096;      // 4M  (row stride of x/y/s-batch)
constexpr long long TDq  = (long long)Tc * Dc;        // 256K
constexpr long long DTq  = (long long)Dc * Tc;        // 256K
constexpr long long HDDq = (long long)DHc * Dc;       // 256K
constexpr long long TBUFq = (long long)Bc * Tc * Dc;  // 1M (split-K slice)

__device__ __forceinline__ void gload16(const void* g, void* l) {
  __builtin_amdgcn_global_load_lds((const __attribute__((address_space(1))) void*)g,
                                   (__attribute__((address_space(3))) void*)l, 16, 0, 0);
}

// ---------------------------------------------------------------------------
// MFMA f16 GEMM: C[m,n] = sum_k A[m,k]*B[n,k]; A,B f16 k-contiguous.
// 128x128 tile, BK=64, 4 waves (2x2 of 64x64), v_mfma_f32_16x16x32_f16.
// LDS [128 rows][64 k], 16B-slot XOR-swizzle (slot ^ row&7): stage via
// pre-swizzled GLOBAL source + linear LDS dest, read with same XOR.
// Batch: z = zb*4 + zh; per-operand element offsets zb*s?b + zh*s?h.
// EPI: 0 = f16, 1 = relu->f16, 2 = relu*aux->f16 (aux shares C offsets), 4 = fp32
// ---------------------------------------------------------------------------
template<int EPI>
__global__ __launch_bounds__(256)
void gemm_f16(const f16_t* __restrict__ A, long long sAb, long long sAh,
              const f16_t* __restrict__ B, long long sBb, long long sBh,
              void* __restrict__ Cv, long long sCb, long long sCh,
              const f16_t* __restrict__ aux,
              int K, int lda, int ldb, int ldc)
{
  __shared__ __align__(16) f16_t As[128 * 64];
  __shared__ __align__(16) f16_t Bs[128 * 64];

  const int zb = blockIdx.z >> 2, zh = blockIdx.z & 3;
  A += zb * sAb + zh * sAh;
  B += zb * sBb + zh * sBh;
  const long long Coff = zb * sCb + zh * sCh;

  const int tid  = threadIdx.x;
  const int lane = tid & 63;
  const int wave = tid >> 6;
  const int wr = wave >> 1, wc = wave & 1;
  const int m0 = blockIdx.y * 128, n0 = blockIdx.x * 128;

  const int lrow  = tid >> 3;   // 0..31
  const int lslot = tid & 7;    // 16B slot in 128B row

  f32x4 acc[4][4] = {};

  for (int k0 = 0; k0 < K; k0 += 64) {
    #pragma unroll
    for (int c = 0; c < 4; ++c) {
      const int row  = c * 32 + lrow;
      const int scol = (lslot ^ (row & 7)) << 3;
      gload16(A + (size_t)(m0 + row) * lda + k0 + scol, As + (c * 256 + tid) * 8);
    }
    #pragma unroll
    for (int c = 0; c < 4; ++c) {
      const int row  = c * 32 + lrow;
      const int scol = (lslot ^ (row & 7)) << 3;
      gload16(B + (size_t)(n0 + row) * ldb + k0 + scol, Bs + (c * 256 + tid) * 8);
    }
    __syncthreads();

    #pragma unroll
    for (int ks = 0; ks < 2; ++ks) {
      f16x8 af[4], bf[4];
      #pragma unroll
      for (int m = 0; m < 4; ++m) {
        const int r  = wr * 64 + m * 16 + (lane & 15);
        const int sl = (ks * 4 + (lane >> 4)) ^ (r & 7);
        af[m] = *(const f16x8*)(As + r * 64 + sl * 8);
      }
      #pragma unroll
      for (int n = 0; n < 4; ++n) {
        const int r  = wc * 64 + n * 16 + (lane & 15);
        const int sl = (ks * 4 + (lane >> 4)) ^ (r & 7);
        bf[n] = *(const f16x8*)(Bs + r * 64 + sl * 8);
      }
      #pragma unroll
      for (int m = 0; m < 4; ++m)
        #pragma unroll
        for (int n = 0; n < 4; ++n)
          acc[m][n] = __builtin_amdgcn_mfma_f32_16x16x32_f16(af[m], bf[n], acc[m][n], 0, 0, 0);
    }
    __syncthreads();
  }

  const int cr   = (lane >> 4) * 4;   // C/D: col=lane&15, row=(lane>>4)*4+reg
  const int ccol = lane & 15;
  if (EPI == 4) {
    float* C = (float*)Cv + Coff;
    #pragma unroll
    for (int m = 0; m < 4; ++m)
      #pragma unroll
      for (int n = 0; n < 4; ++n)
        #pragma unroll
        for (int r = 0; r < 4; ++r)
          C[(long long)(m0 + wr * 64 + m * 16 + cr + r) * ldc
            + (n0 + wc * 64 + n * 16 + ccol)] = acc[m][n][r];
  } else {
    f16_t* C = (f16_t*)Cv + Coff;
    const f16_t* X = (EPI == 2) ? aux + Coff : nullptr;
    #pragma unroll
    for (int m = 0; m < 4; ++m)
      #pragma unroll
      for (int n = 0; n < 4; ++n)
        #pragma unroll
        for (int r = 0; r < 4; ++r) {
          const long long off = (long long)(m0 + wr * 64 + m * 16 + cr + r) * ldc
                                + (n0 + wc * 64 + n * 16 + ccol);
          float val = acc[m][n][r];
          if (EPI >= 1) val = fmaxf(val, 0.0f);
          if (EPI == 2) val *= (float)X[off];
          C[off] = (f16_t)val;
        }
  }
}

// fp32 [R][C] -> f16 [C][R], batched over z
__global__ __launch_bounds__(256)
void transpose_f32_f16(const float* __restrict__ in, f16_t* __restrict__ out,
                       int R, int C, long long sIn, long long sOut)
{
  __shared__ float tile[32][33];
  in  += (long long)blockIdx.z * sIn;
  out += (long long)blockIdx.z * sOut;
  const int c0 = blockIdx.x * 32, r0 = blockIdx.y * 32;
  const int tx = threadIdx.x & 31, ty = threadIdx.x >> 5;
  #pragma unroll
  for (int i = 0; i < 32; i += 8)
    tile[ty + i][tx] = in[(long long)(r0 + ty + i) * C + (c0 + tx)];
  __syncthreads();
  #pragma unroll
  for (int i = 0; i < 32; i += 8)
    out[(long long)(c0 + ty + i) * R + (r0 + tx)] = (f16_t)tile[tx][ty + i];
}

// f16 [R][C] -> f16 [C][R], batched over z
__global__ __launch_bounds__(256)
void transpose_f16(const f16_t* __restrict__ in, f16_t* __restrict__ out,
                   int R, int C, long long sIn, long long sOut)
{
  __shared__ f16_t tile[32][34];
  in  += (long long)blockIdx.z * sIn;
  out += (long long)blockIdx.z * sOut;
  const int c0 = blockIdx.x * 32, r0 = blockIdx.y * 32;
  const int tx = threadIdx.x & 31, ty = threadIdx.x >> 5;
  #pragma unroll
  for (int i = 0; i < 32; i += 8)
    tile[ty + i][tx] = in[(long long)(r0 + ty + i) * C + (c0 + tx)];
  __syncthreads();
  #pragma unroll
  for (int i = 0; i < 32; i += 8)
    out[(long long)(c0 + ty + i) * R + (r0 + tx)] = tile[tx][ty + i];
}

__global__ __launch_bounds__(256)
void init_tables(float* __restrict__ cosT, float* __restrict__ sinT)
{
  const int i = blockIdx.x * 256 + threadIdx.x;  // < T*512
  const int j = i & (HALFc - 1);
  const int t = i >> 9;
  const float inv = expf(-(float)j * (9.210340371976184f / 512.0f));  // ln(1e4)/512
  const float ang = (float)t * inv;
  cosT[i] = cosf(ang);
  sinT[i] = sinf(ang);
}

// RoPE over x_all [B*T][H*Dh]; pairs (e, e+512) within each head's 1024 block
__global__ __launch_bounds__(256)
void rope_f16(const f16_t* __restrict__ x, f16_t* __restrict__ xr,
              const float* __restrict__ cosT, const float* __restrict__ sinT)
{
  const int i   = blockIdx.x * 256 + threadIdx.x;  // < B*T*H*128
  const int e4  = i & 127;
  const int bth = i >> 7;          // bt*4 + h
  const int t   = (bth >> 2) & (Tc - 1);
  const f32x4 c = ((const f32x4*)cosT)[t * 128 + e4];
  const f32x4 s = ((const f32x4*)sinT)[t * 128 + e4];
  const long long base = (long long)(bth >> 2) * 4096 + (bth & 3) * DHc + e4 * 4;
  const f16x4 x0 = *(const f16x4*)(x + base);
  const f16x4 x1 = *(const f16x4*)(x + base + HALFc);
  f16x4 r0, r1;
  #pragma unroll
  for (int j = 0; j < 4; ++j) {
    const float a = (float)x0[j], b = (float)x1[j];
    r0[j] = (f16_t)(a * c[j] - b * s[j]);
    r1[j] = (f16_t)(b * c[j] + a * s[j]);
  }
  *(f16x4*)(xr + base) = r0;
  *(f16x4*)(xr + base + HALFc) = r1;
}

__device__ __forceinline__ void block_stats(float val, float* red, float& mean, float& inv_std)
{
  float s1 = val, s2 = val * val;
  #pragma unroll
  for (int o = 1; o < 64; o <<= 1) {
    s1 += __shfl_xor(s1, o);
    s2 += __shfl_xor(s2, o);
  }
  const int lane = threadIdx.x & 63;
  const int w = threadIdx.x >> 6;
  if (lane == 0) { red[w * 2] = s1; red[w * 2 + 1] = s2; }
  __syncthreads();
  s1 = red[0] + red[2] + red[4] + red[6];
  s2 = red[1] + red[3] + red[5] + red[7];
  mean = s1 * (1.0f / Dc);
  const float var = s2 * (1.0f / Dc) - mean * mean;
  inv_std = 1.0f / sqrtf(var + EPS);
  __syncthreads();
}

__global__ __launch_bounds__(256)
void embed_ln(const int* __restrict__ tokens, const float* __restrict__ emb,
              f16_t* __restrict__ v)
{
  __shared__ float red[8];
  const int row = blockIdx.x;
  const int d = threadIdx.x;
  const float val = emb[(long long)tokens[row] * Dc + d];
  float m, is;
  block_stats(val, red, m, is);
  v[(long long)row * Dc + d] = (f16_t)((val - m) * is);
}

// v = LN(v + LN(sum_{z<4} t_z)); t split-K slices fp32
__global__ __launch_bounds__(256)
void fuse_ln4(f16_t* __restrict__ v, const float* __restrict__ t)
{
  __shared__ float red[8];
  const long long row = blockIdx.x;
  const int d = threadIdx.x;
  const long long off = row * Dc + d;
  const float tv = t[off] + t[off + TBUFq] + t[off + 2 * TBUFq] + t[off + 3 * TBUFq];
  float m1, is1;
  block_stats(tv, red, m1, is1);
  const float u = (tv - m1) * is1;
  const float wv = (float)v[off] + u;
  float m2, is2;
  block_stats(wv, red, m2, is2);
  v[off] = (f16_t)((wv - m2) * is2);
}

}  // anonymous namespace

extern "C" void kernel_launch(void* const* d_in, const int* in_sizes, int n_in,
                              void* d_out, int out_size, void* d_ws, size_t ws_size,
                              hipStream_t stream)
{
  (void)in_sizes; (void)n_in; (void)out_size; (void)ws_size;
  const int*   tokens  = (const int*)d_in[0];
  const float* emb_w   = (const float*)d_in[1];
  const float* E       = (const float*)d_in[2];
  const float* Dx      = (const float*)d_in[3];
  const float* Dy      = (const float*)d_in[4];
  const float* readout = (const float*)d_in[5];
  float* out = (float*)d_out;

  // Workspace carve-up (~110 MB; harness poison fill shows ws = 256 MiB)
  char* w = (char*)d_ws;
  auto carve = [&](size_t bytes) { char* p = w; w += (bytes + 255) & ~(size_t)255; return p; };
  float* cosT = (float*)carve((size_t)Tc * HALFc * 4);        // 2 MB
  float* sinT = (float*)carve((size_t)Tc * HALFc * 4);        // 2 MB
  f16_t* v    = (f16_t*)carve((size_t)Bc * Tc * Dc * 2);      // 2 MB
  f16_t* vT   = (f16_t*)carve((size_t)Bc * Dc * Tc * 2);      // 2 MB
  f16_t* x    = (f16_t*)carve((size_t)Bc * Tc * 4096 * 2);    // 32 MB [B*T][H*Dh]
  f16_t* xr   = (f16_t*)carve((size_t)Bc * Tc * 4096 * 2);    // 32 MB (also y)
  f16_t* s    = (f16_t*)carve((size_t)Bc * Hc * Tc * Tc * 2); // 32 MB [B*H][T][T]
  f16_t* a    = (f16_t*)carve((size_t)Bc * Tc * Hc * Dc * 2); // 8 MB [B*T][H*D]
  float* t    = (float*)carve((size_t)4 * TBUFq * 4);         // 16 MB (4 split-K slices)
  f16_t* DxT  = (f16_t*)carve((size_t)Hc * DHc * Dc * 2);     // 2 MB [H*Dh][D]
  f16_t* DyT  = (f16_t*)carve((size_t)Hc * DHc * Dc * 2);     // 2 MB [H][Dh][D]
  f16_t* ET   = (f16_t*)carve((size_t)Dc * Hc * DHc * 2);     // 2 MB [D][H*Dh]
  f16_t* RT   = (f16_t*)carve((size_t)Vc * Dc * 2);           // 128 KB

  // One-time prep
  transpose_f32_f16<<<dim3(32, 8, Hc), 256, 0, stream>>>(Dx, DxT, Dc, DHc, HDDq, HDDq);
  transpose_f32_f16<<<dim3(32, 8, Hc), 256, 0, stream>>>(Dy, DyT, Dc, DHc, HDDq, HDDq);
  transpose_f32_f16<<<dim3(8, 128, 1), 256, 0, stream>>>(E, ET, 4096, Dc, 0, 0);
  transpose_f32_f16<<<dim3(8, 8, 1), 256, 0, stream>>>(readout, RT, Dc, Vc, 0, 0);
  init_tables<<<(Tc * HALFc) / 256, 256, 0, stream>>>(cosT, sinT);
  embed_ln<<<Bc * Tc, 256, 0, stream>>>(tokens, emb_w, v);
  transpose_f16<<<dim3(8, 32, Bc), 256, 0, stream>>>(v, vT, Tc, Dc, TDq, DTq);

  for (int l = 0; l < Lc; ++l) {
    // 1) x = relu(v . DxT^T): [4096 x 4096], K=256 — all heads in one GEMM
    gemm_f16<1><<<dim3(32, 32, 1), 256, 0, stream>>>(
        v, 0, 0, DxT, 0, 0, x, 0, 0, nullptr, Dc, Dc, Dc, 4096);
    // 2) xr = RoPE(x)
    rope_f16<<<(Bc * Tc * Hc * 128) / 256, 256, 0, stream>>>(x, xr, cosT, sinT);
    // 3) s[b,h] = xr_bh . xr_bh^T: [1024 x 1024], K=1024, z=16
    gemm_f16<0><<<dim3(8, 8, 16), 256, 0, stream>>>(
        xr, T4q, DHc, xr, T4q, DHc, s, 4 * TTq, TTq, nullptr, DHc, 4096, 4096, Tc);
    // 4) a[b,:,h,:] = s[b,h] . v_b: [1024 x 256], K=1024, z=16 (B = vT)
    gemm_f16<0><<<dim3(2, 8, 16), 256, 0, stream>>>(
        s, 4 * TTq, TTq, vT, DTq, 0, a, (long long)Tc * 1024, Dc, nullptr,
        Tc, Tc, Tc, 1024);
    // 5) y = relu(a_h . DyT_h^T) * x: [4096 x 1024] per head, z=4 (y -> xr)
    gemm_f16<2><<<dim3(8, 32, 4), 256, 0, stream>>>(
        a, 0, Dc, DyT, 0, HDDq, xr, 0, DHc, x, Dc, 1024, Dc, 4096);
    // 6) t_z = y_h . ET_h^T: [4096 x 256] fp32, K=1024, split-K over heads z=4
    gemm_f16<4><<<dim3(2, 32, 4), 256, 0, stream>>>(
        xr, 0, DHc, ET, 0, DHc, t, 0, TBUFq, nullptr, DHc, 4096, 4096, Dc);
    // 7) v = LN(v + LN(sum_z t_z)); 8) refresh vT
    fuse_ln4<<<Bc * Tc, 256, 0, stream>>>(v, t);
    transpose_f16<<<dim3(8, 32, Bc), 256, 0, stream>>>(v, vT, Tc, Dc, TDq, DTq);
  }

  // out = v . RT^T: [4096 x 256] fp32, K=256
  gemm_f16<4><<<dim3(2, 32, 1), 256, 0, stream>>>(
      v, 0, 0, RT, 0, 0, out, 0, 0, nullptr, Dc, Dc, Dc, Vc);
}

// Round 4
// 887.516 us; speedup vs baseline: 21.3185x; 1.1777x over previous
//
#include <hip/hip_runtime.h>
#include <cstdint>

namespace {

typedef _Float16 f16_t;
typedef _Float16 f16x8 __attribute__((ext_vector_type(8)));
typedef _Float16 f16x4 __attribute__((ext_vector_type(4)));
typedef float    f32x4 __attribute__((ext_vector_type(4)));

constexpr int Bc = 4, Tc = 1024, Hc = 4, Dc = 256, DHc = 1024, Lc = 6, Vc = 256;
constexpr int HALFc = 512;
constexpr float EPS = 1e-5f;
constexpr long long T4q  = (long long)Tc * 4096;      // 4M (row stride of x/y per b)
constexpr long long TDq  = (long long)Tc * Dc;        // 256K
constexpr long long DTq  = (long long)Dc * Tc;        // 256K
constexpr long long HDDq = (long long)DHc * Dc;       // 256K
constexpr long long TBUFq = (long long)Bc * Tc * Dc;  // 1M (split-K slice)

__device__ __forceinline__ void gload16(const void* g, void* l) {
  __builtin_amdgcn_global_load_lds((const __attribute__((address_space(1))) void*)g,
                                   (__attribute__((address_space(3))) void*)l, 16, 0, 0);
}

// ---------------------------------------------------------------------------
// MFMA f16 GEMM. 128x128 tile, BK=64, 4 waves (2x2 of 64x64), 16x16x32 MFMA.
// BKMAJ=false: C[m,n] = sum_k A[m,k]*B[n,k]   (B k-contiguous, [N][K])
// BKMAJ=true : C[m,n] = sum_k A[m,k]*B[k,n]   (B k-major, [K][N], ld=ldb)
// LDS [128 rows][64 k], 16B-slot XOR swizzle (slot ^ row&7). A (and B when
// !BKMAJ) staged via global_load_lds with pre-swizzled global source; BKMAJ
// B staged via reg + packed ds_write_b32 into the same swizzled layout
// (bank pattern: 32 lanes cover 32 banks across 2 rows -> 2-way, free).
// Batch: z = zb*4 + zh; per-operand element offsets zb*s?b + zh*s?h.
// EPI: 0 = f16, 1 = relu->f16, 2 = relu*aux->f16 (aux shares C offsets), 4 = fp32
// ---------------------------------------------------------------------------
template<int EPI, bool BKMAJ>
__global__ __launch_bounds__(256)
void gemm_f16(const f16_t* __restrict__ A, long long sAb, long long sAh,
              const f16_t* __restrict__ B, long long sBb, long long sBh,
              void* __restrict__ Cv, long long sCb, long long sCh,
              const f16_t* __restrict__ aux,
              int K, int lda, int ldb, int ldc)
{
  __shared__ __align__(16) f16_t As[128 * 64];
  __shared__ __align__(16) f16_t Bs[128 * 64];

  const int zb = blockIdx.z >> 2, zh = blockIdx.z & 3;
  A += zb * sAb + zh * sAh;
  B += zb * sBb + zh * sBh;
  const long long Coff = zb * sCb + zh * sCh;

  const int tid  = threadIdx.x;
  const int lane = tid & 63;
  const int wave = tid >> 6;
  const int wr = wave >> 1, wc = wave & 1;
  const int m0 = blockIdx.y * 128, n0 = blockIdx.x * 128;

  const int lrow  = tid >> 3;   // 0..31
  const int lslot = tid & 7;    // 16B slot in 128B row

  f32x4 acc[4][4] = {};

  for (int k0 = 0; k0 < K; k0 += 64) {
    #pragma unroll
    for (int c = 0; c < 4; ++c) {
      const int row  = c * 32 + lrow;
      const int scol = (lslot ^ (row & 7)) << 3;
      gload16(A + (size_t)(m0 + row) * lda + k0 + scol, As + (c * 256 + tid) * 8);
    }
    if (!BKMAJ) {
      #pragma unroll
      for (int c = 0; c < 4; ++c) {
        const int row  = c * 32 + lrow;
        const int scol = (lslot ^ (row & 7)) << 3;
        gload16(B + (size_t)(n0 + row) * ldb + k0 + scol, Bs + (c * 256 + tid) * 8);
      }
    } else {
      // B tile from k-major [K][N]: thread handles k-pair kp=tid&31, n-group
      // g=tid>>5 (8 cols). value(row=n, k) lives at f16-idx
      // n*64 + ((k>>3)^(n&7))*8 + (k&7); k=2kp{,+1} share a slot -> b32 pack.
      const int kp = tid & 31, g = tid >> 5;
      #pragma unroll
      for (int p = 0; p < 2; ++p) {
        const int nb = p * 64 + g * 8;
        const int k  = kp * 2;
        const f16x8 r0 = *(const f16x8*)(B + (size_t)(k0 + k) * ldb + n0 + nb);
        const f16x8 r1 = *(const f16x8*)(B + (size_t)(k0 + k + 1) * ldb + n0 + nb);
        #pragma unroll
        for (int j = 0; j < 8; ++j) {
          const int n = nb + j;
          union { f16_t h[2]; unsigned int u; } pk;
          pk.h[0] = r0[j]; pk.h[1] = r1[j];
          ((unsigned int*)Bs)[n * 32 + (((kp >> 2) ^ (n & 7)) << 2) + (kp & 3)] = pk.u;
        }
      }
    }
    __syncthreads();

    #pragma unroll
    for (int ks = 0; ks < 2; ++ks) {
      f16x8 af[4], bf[4];
      #pragma unroll
      for (int m = 0; m < 4; ++m) {
        const int r  = wr * 64 + m * 16 + (lane & 15);
        const int sl = (ks * 4 + (lane >> 4)) ^ (r & 7);
        af[m] = *(const f16x8*)(As + r * 64 + sl * 8);
      }
      #pragma unroll
      for (int n = 0; n < 4; ++n) {
        const int r  = wc * 64 + n * 16 + (lane & 15);
        const int sl = (ks * 4 + (lane >> 4)) ^ (r & 7);
        bf[n] = *(const f16x8*)(Bs + r * 64 + sl * 8);
      }
      #pragma unroll
      for (int m = 0; m < 4; ++m)
        #pragma unroll
        for (int n = 0; n < 4; ++n)
          acc[m][n] = __builtin_amdgcn_mfma_f32_16x16x32_f16(af[m], bf[n], acc[m][n], 0, 0, 0);
    }
    __syncthreads();
  }

  const int cr   = (lane >> 4) * 4;   // C/D: col=lane&15, row=(lane>>4)*4+reg
  const int ccol = lane & 15;
  if (EPI == 4) {
    float* C = (float*)Cv + Coff;
    #pragma unroll
    for (int m = 0; m < 4; ++m)
      #pragma unroll
      for (int n = 0; n < 4; ++n)
        #pragma unroll
        for (int r = 0; r < 4; ++r)
          C[(long long)(m0 + wr * 64 + m * 16 + cr + r) * ldc
            + (n0 + wc * 64 + n * 16 + ccol)] = acc[m][n][r];
  } else {
    f16_t* C = (f16_t*)Cv + Coff;
    const f16_t* X = (EPI == 2) ? aux + Coff : nullptr;
    #pragma unroll
    for (int m = 0; m < 4; ++m)
      #pragma unroll
      for (int n = 0; n < 4; ++n)
        #pragma unroll
        for (int r = 0; r < 4; ++r) {
          const long long off = (long long)(m0 + wr * 64 + m * 16 + cr + r) * ldc
                                + (n0 + wc * 64 + n * 16 + ccol);
          float val = acc[m][n][r];
          if (EPI >= 1) val = fmaxf(val, 0.0f);
          if (EPI == 2) val *= (float)X[off];
          C[off] = (f16_t)val;
        }
  }
}

// fp32 [R][C] -> f16 [C][R], batched over z
__global__ __launch_bounds__(256)
void transpose_f32_f16(const float* __restrict__ in, f16_t* __restrict__ out,
                       int R, int C, long long sIn, long long sOut)
{
  __shared__ float tile[32][33];
  in  += (long long)blockIdx.z * sIn;
  out += (long long)blockIdx.z * sOut;
  const int c0 = blockIdx.x * 32, r0 = blockIdx.y * 32;
  const int tx = threadIdx.x & 31, ty = threadIdx.x >> 5;
  #pragma unroll
  for (int i = 0; i < 32; i += 8)
    tile[ty + i][tx] = in[(long long)(r0 + ty + i) * C + (c0 + tx)];
  __syncthreads();
  #pragma unroll
  for (int i = 0; i < 32; i += 8)
    out[(long long)(c0 + ty + i) * R + (r0 + tx)] = (f16_t)tile[tx][ty + i];
}

// f16 [R][C] -> f16 [C][R], batched over z
__global__ __launch_bounds__(256)
void transpose_f16(const f16_t* __restrict__ in, f16_t* __restrict__ out,
                   int R, int C, long long sIn, long long sOut)
{
  __shared__ f16_t tile[32][34];
  in  += (long long)blockIdx.z * sIn;
  out += (long long)blockIdx.z * sOut;
  const int c0 = blockIdx.x * 32, r0 = blockIdx.y * 32;
  const int tx = threadIdx.x & 31, ty = threadIdx.x >> 5;
  #pragma unroll
  for (int i = 0; i < 32; i += 8)
    tile[ty + i][tx] = in[(long long)(r0 + ty + i) * C + (c0 + tx)];
  __syncthreads();
  #pragma unroll
  for (int i = 0; i < 32; i += 8)
    out[(long long)(c0 + ty + i) * R + (r0 + tx)] = tile[tx][ty + i];
}

__global__ __launch_bounds__(256)
void init_tables(float* __restrict__ cosT, float* __restrict__ sinT)
{
  const int i = blockIdx.x * 256 + threadIdx.x;  // < T*512
  const int j = i & (HALFc - 1);
  const int t = i >> 9;
  const float inv = expf(-(float)j * (9.210340371976184f / 512.0f));  // ln(1e4)/512
  const float ang = (float)t * inv;
  cosT[i] = cosf(ang);
  sinT[i] = sinf(ang);
}

// RoPE over x_all [B*T][H*Dh]; pairs (e, e+512) within each head's 1024 block
__global__ __launch_bounds__(256)
void rope_f16(const f16_t* __restrict__ x, f16_t* __restrict__ xr,
              const float* __restrict__ cosT, const float* __restrict__ sinT)
{
  const int i   = blockIdx.x * 256 + threadIdx.x;  // < B*T*H*128
  const int e4  = i & 127;
  const int bth = i >> 7;          // bt*4 + h
  const int t   = (bth >> 2) & (Tc - 1);
  const f32x4 c = ((const f32x4*)cosT)[t * 128 + e4];
  const f32x4 s = ((const f32x4*)sinT)[t * 128 + e4];
  const long long base = (long long)(bth >> 2) * 4096 + (bth & 3) * DHc + e4 * 4;
  const f16x4 x0 = *(const f16x4*)(x + base);
  const f16x4 x1 = *(const f16x4*)(x + base + HALFc);
  f16x4 r0, r1;
  #pragma unroll
  for (int j = 0; j < 4; ++j) {
    const float a = (float)x0[j], b = (float)x1[j];
    r0[j] = (f16_t)(a * c[j] - b * s[j]);
    r1[j] = (f16_t)(b * c[j] + a * s[j]);
  }
  *(f16x4*)(xr + base) = r0;
  *(f16x4*)(xr + base + HALFc) = r1;
}

__device__ __forceinline__ void block_stats(float val, float* red, float& mean, float& inv_std)
{
  float s1 = val, s2 = val * val;
  #pragma unroll
  for (int o = 1; o < 64; o <<= 1) {
    s1 += __shfl_xor(s1, o);
    s2 += __shfl_xor(s2, o);
  }
  const int lane = threadIdx.x & 63;
  const int w = threadIdx.x >> 6;
  if (lane == 0) { red[w * 2] = s1; red[w * 2 + 1] = s2; }
  __syncthreads();
  s1 = red[0] + red[2] + red[4] + red[6];
  s2 = red[1] + red[3] + red[5] + red[7];
  mean = s1 * (1.0f / Dc);
  const float var = s2 * (1.0f / Dc) - mean * mean;
  inv_std = 1.0f / sqrtf(var + EPS);
  __syncthreads();
}

__global__ __launch_bounds__(256)
void embed_ln(const int* __restrict__ tokens, const float* __restrict__ emb,
              f16_t* __restrict__ v)
{
  __shared__ float red[8];
  const int row = blockIdx.x;
  const int d = threadIdx.x;
  const float val = emb[(long long)tokens[row] * Dc + d];
  float m, is;
  block_stats(val, red, m, is);
  v[(long long)row * Dc + d] = (f16_t)((val - m) * is);
}

// v = LN(v + LN(sum_{z<4} t_z)); t split-K slices fp32
__global__ __launch_bounds__(256)
void fuse_ln4(f16_t* __restrict__ v, const float* __restrict__ t)
{
  __shared__ float red[8];
  const long long row = blockIdx.x;
  const int d = threadIdx.x;
  const long long off = row * Dc + d;
  const float tv = t[off] + t[off + TBUFq] + t[off + 2 * TBUFq] + t[off + 3 * TBUFq];
  float m1, is1;
  block_stats(tv, red, m1, is1);
  const float u = (tv - m1) * is1;
  const float wv = (float)v[off] + u;
  float m2, is2;
  block_stats(wv, red, m2, is2);
  v[off] = (f16_t)((wv - m2) * is2);
}

}  // anonymous namespace

extern "C" void kernel_launch(void* const* d_in, const int* in_sizes, int n_in,
                              void* d_out, int out_size, void* d_ws, size_t ws_size,
                              hipStream_t stream)
{
  (void)in_sizes; (void)n_in; (void)out_size; (void)ws_size;
  const int*   tokens  = (const int*)d_in[0];
  const float* emb_w   = (const float*)d_in[1];
  const float* E       = (const float*)d_in[2];
  const float* Dx      = (const float*)d_in[3];
  const float* Dy      = (const float*)d_in[4];
  const float* readout = (const float*)d_in[5];
  float* out = (float*)d_out;

  // Workspace carve-up (~90 MB)
  char* w = (char*)d_ws;
  auto carve = [&](size_t bytes) { char* p = w; w += (bytes + 255) & ~(size_t)255; return p; };
  float* cosT = (float*)carve((size_t)Tc * HALFc * 4);        // 2 MB
  float* sinT = (float*)carve((size_t)Tc * HALFc * 4);        // 2 MB
  f16_t* v    = (f16_t*)carve((size_t)Bc * Tc * Dc * 2);      // 2 MB
  f16_t* vT   = (f16_t*)carve((size_t)Bc * Dc * Tc * 2);      // 2 MB
  f16_t* x    = (f16_t*)carve((size_t)Bc * Tc * 4096 * 2);    // 32 MB [B*T][H*Dh]
  f16_t* xr   = (f16_t*)carve((size_t)Bc * Tc * 4096 * 2);    // 32 MB (also y)
  f16_t* WT   = (f16_t*)carve((size_t)Bc * Dc * 4096 * 2);    // 8 MB [B][D][H*Dh]
  f16_t* a    = (f16_t*)carve((size_t)Bc * Tc * Hc * Dc * 2); // 8 MB [B*T][H*D]
  float* t    = (float*)carve((size_t)4 * TBUFq * 4);         // 16 MB (split-K slices)
  f16_t* DxT  = (f16_t*)carve((size_t)Hc * DHc * Dc * 2);     // 2 MB [H*Dh][D]
  f16_t* DyT  = (f16_t*)carve((size_t)Hc * DHc * Dc * 2);     // 2 MB [H][Dh][D]
  f16_t* ET   = (f16_t*)carve((size_t)Dc * Hc * DHc * 2);     // 2 MB [D][H*Dh]
  f16_t* RT   = (f16_t*)carve((size_t)Vc * Dc * 2);           // 128 KB

  // One-time prep
  transpose_f32_f16<<<dim3(32, 8, Hc), 256, 0, stream>>>(Dx, DxT, Dc, DHc, HDDq, HDDq);
  transpose_f32_f16<<<dim3(32, 8, Hc), 256, 0, stream>>>(Dy, DyT, Dc, DHc, HDDq, HDDq);
  transpose_f32_f16<<<dim3(8, 128, 1), 256, 0, stream>>>(E, ET, 4096, Dc, 0, 0);
  transpose_f32_f16<<<dim3(8, 8, 1), 256, 0, stream>>>(readout, RT, Dc, Vc, 0, 0);
  init_tables<<<(Tc * HALFc) / 256, 256, 0, stream>>>(cosT, sinT);
  embed_ln<<<Bc * Tc, 256, 0, stream>>>(tokens, emb_w, v);
  transpose_f16<<<dim3(8, 32, Bc), 256, 0, stream>>>(v, vT, Tc, Dc, TDq, DTq);

  for (int l = 0; l < Lc; ++l) {
    // 1) x = relu(v . DxT^T): [4096 x 4096], K=256 — all heads in one GEMM
    gemm_f16<1, false><<<dim3(32, 32, 1), 256, 0, stream>>>(
        v, 0, 0, DxT, 0, 0, x, 0, 0, nullptr, Dc, Dc, Dc, 4096);
    // 2) xr = RoPE(x)
    rope_f16<<<(Bc * Tc * Hc * 128) / 256, 256, 0, stream>>>(x, xr, cosT, sinT);
    // 3) WT[b] = vT[b] . xr[b]  (B k-major): [256 x 4096], K=T=1024, z=4
    //    WT[b,d,he] = sum_t v[b,t,d] * xr[b,t,he]
    gemm_f16<0, true><<<dim3(32, 2, 4), 256, 0, stream>>>(
        vT, 0, DTq, xr, 0, T4q, WT, 0, (long long)Dc * 4096, nullptr,
        Tc, Tc, 4096, 4096);
    // 4) a[b,:,h,:] = xr_bh . WT_bh^T: [1024 x 256], K=Dh=1024, z=16
    gemm_f16<0, false><<<dim3(2, 8, 16), 256, 0, stream>>>(
        xr, T4q, DHc, WT, (long long)Dc * 4096, DHc, a, (long long)Tc * 1024, Dc,
        nullptr, DHc, 4096, 4096, 1024);
    // 5) y = relu(a_h . DyT_h^T) * x: [4096 x 1024] per head, z=4 (y -> xr)
    gemm_f16<2, false><<<dim3(8, 32, 4), 256, 0, stream>>>(
        a, 0, Dc, DyT, 0, HDDq, xr, 0, DHc, x, Dc, 1024, Dc, 4096);
    // 6) t_z = y_h . ET_h^T: [4096 x 256] fp32, K=1024, split-K over heads z=4
    gemm_f16<4, false><<<dim3(2, 32, 4), 256, 0, stream>>>(
        xr, 0, DHc, ET, 0, DHc, t, 0, TBUFq, nullptr, DHc, 4096, 4096, Dc);
    // 7) v = LN(v + LN(sum_z t_z)); 8) refresh vT
    fuse_ln4<<<Bc * Tc, 256, 0, stream>>>(v, t);
    transpose_f16<<<dim3(8, 32, Bc), 256, 0, stream>>>(v, vT, Tc, Dc, TDq, DTq);
  }

  // out = v . RT^T: [4096 x 256] fp32, K=256
  gemm_f16<4, false><<<dim3(2, 32, 1), 256, 0, stream>>>(
      v, 0, 0, RT, 0, 0, out, 0, 0, nullptr, Dc, Dc, Dc, Vc);
}